// Round 6
// baseline (405.102 us; speedup 1.0000x reference)
//
#include <hip/hip_runtime.h>
#include <hip/hip_bf16.h>
#include <hip/hip_cooperative_groups.h>

namespace cg = cooperative_groups;

#define D_IN 256
#define D_OUT 64
#define BN_EPS 1e-5f

#define BINSHIFT 8                 // 256 nodes per bin
#define BINCAP 4608                // >= max edges per bin (mean 4092, +8 sigma)

typedef __attribute__((ext_vector_type(4))) float floatx4;
typedef __attribute__((ext_vector_type(8))) __bf16 bf16x8;
typedef __attribute__((ext_vector_type(4))) unsigned uintx4;

// ---- prep: zero bincur + bn params + W split (MFMA B-fragment order) -------
__global__ __launch_bounds__(256) void k_prep(
        const float* __restrict__ W, __bf16* __restrict__ whi, __bf16* __restrict__ wlo,
        const float* __restrict__ bias, const float* __restrict__ gamma,
        const float* __restrict__ beta, const float* __restrict__ rmean,
        const float* __restrict__ rvar,
        float* __restrict__ bnsc, float* __restrict__ bnsh,
        int* __restrict__ bincur, int nbins) {
    int b = blockIdx.x, t = threadIdx.x;
    if (b < 2) {
        int i = b * 256 + t;
        if (i < nbins) bincur[i] = 0;
        if (b == 1 && t < D_OUT) {
            float sc = rsqrtf(rvar[t] + BN_EPS) * gamma[t];
            bnsc[t] = sc;
            bnsh[t] = (bias[t] - rmean[t]) * sc + beta[t];
        }
        return;
    }
    int tid = (b - 2) * 256 + t;   // 0..2047
    int lane = tid & 63, c = (tid >> 6) & 7, tt = tid >> 9;
    int row = tt * 16 + (lane & 15);
    int k0 = c * 32 + (lane >> 4) * 8;
    size_t dst = (size_t)tid * 8;
    #pragma unroll
    for (int j = 0; j < 8; ++j) {
        float w = W[(size_t)row * D_IN + k0 + j];
        __bf16 h = (__bf16)w;
        whi[dst + j] = h;
        wlo[dst + j] = (__bf16)(w - (float)h);
    }
}

// ---- fused build: partition -> scan -> per-bin CSR fill (cooperative) ------
// Phase 1: each block partitions a chunk of edges into per-bin segments
//          (packed (src<<8 | tgt&255)), reserving slots via bincur atomics.
// Phase 2: block 0 exclusive-scans bin counts -> binoff, writes off[N]=E.
// Phase 3: block b = bin b: node-level counts, local scan -> off/dinv,
//          scatter srcs in CSR order.
__global__ __launch_bounds__(256) void k_build(
        const int* __restrict__ ei, int* __restrict__ bincur,
        unsigned* __restrict__ pairs, int* __restrict__ binoff,
        int* __restrict__ off, float* __restrict__ dinv,
        int* __restrict__ srcs, int E, int N, int nbins) {
    __shared__ int hist[512];
    __shared__ int base[512];
    __shared__ int curs[256];
    int t = threadIdx.x, b = blockIdx.x;
    cg::grid_group grid = cg::this_grid();

    // ---------------- phase 1: binned partition ----------------
    int nb = gridDim.x;                       // == nbins
    int chunk = (E + nb - 1) / nb;            // 4093 for E=1.6M, nb=391
    int e0 = b * chunk;
    int eend = e0 + chunk; if (eend > E) eend = E;

    for (int j = t; j < nbins; j += 256) hist[j] = 0;
    __syncthreads();

    int cols[16];
    int ranks[16];
    #pragma unroll
    for (int i = 0; i < 16; ++i) {
        int e = e0 + i * 256 + t;
        if (e < eend) {
            int c = ei[E + e];
            cols[i] = c;
            ranks[i] = atomicAdd(&hist[c >> BINSHIFT], 1);
        }
    }
    __syncthreads();
    for (int j = t; j < nbins; j += 256)
        base[j] = atomicAdd(&bincur[j], hist[j]);
    __syncthreads();
    #pragma unroll
    for (int i = 0; i < 16; ++i) {
        int e = e0 + i * 256 + t;
        if (e < eend) {
            int c = cols[i];
            int bin = c >> BINSHIFT;
            int pos = base[bin] + ranks[i];
            if (pos >= BINCAP) pos = BINCAP - 1;     // never-hit safety
            pairs[(size_t)bin * BINCAP + pos] =
                ((unsigned)ei[e] << 8) | (unsigned)(c & 255);
        }
    }
    // cold overflow path (chunk > 4096 edges) — direct global reservation
    for (int e = e0 + 16 * 256 + t; e < eend; e += 256) {
        int c = ei[E + e];
        int bin = c >> BINSHIFT;
        int pos = atomicAdd(&bincur[bin], 1);
        if (pos >= BINCAP) pos = BINCAP - 1;
        pairs[(size_t)bin * BINCAP + pos] =
            ((unsigned)ei[e] << 8) | (unsigned)(c & 255);
    }

    grid.sync();

    // ---------------- phase 2: scan of bin counts (block 0) ----------------
    if (b == 0) {
        int i0 = 2 * t, i1 = 2 * t + 1;
        int v0 = (i0 < nbins) ? bincur[i0] : 0;
        int v1 = (i1 < nbins) ? bincur[i1] : 0;
        int s = v0 + v1;
        base[t] = s;
        __syncthreads();
        for (int o = 1; o < 256; o <<= 1) {
            int v = (t >= o) ? base[t - o] : 0;
            __syncthreads();
            base[t] += v;
            __syncthreads();
        }
        int excl = base[t] - s;
        if (i0 < nbins) binoff[i0] = excl;
        if (i1 < nbins) binoff[i1] = excl + v0;
        if (t == 255) off[N] = base[255];
    }

    grid.sync();

    // ---------------- phase 3: per-bin CSR fill (block b = bin b) ----------
    hist[t] = 0;
    __syncthreads();
    int cnt = bincur[b];
    const unsigned* bp = pairs + (size_t)b * BINCAP;
    for (int p = t; p < cnt; p += 256)
        atomicAdd(&hist[bp[p] & 255u], 1);
    __syncthreads();
    int own = hist[t];
    base[t] = own;
    __syncthreads();
    for (int o = 1; o < 256; o <<= 1) {
        int v = (t >= o) ? base[t - o] : 0;
        __syncthreads();
        base[t] += v;
        __syncthreads();
    }
    int nbase = binoff[b] + base[t] - own;
    int node = (b << BINSHIFT) + t;
    curs[t] = nbase;
    if (node < N) {
        off[node] = nbase;
        dinv[node] = rsqrtf((float)(own + 1));   // +1 self-loop
    }
    __syncthreads();
    for (int p = t; p < cnt; p += 256) {
        unsigned v = bp[p];
        int pos = atomicAdd(&curs[v & 255u], 1);
        srcs[pos] = (int)(v >> 8);
    }
}

// ---- y(bf16) = dinv * (x @ W^T) via split-bf16 MFMA; no LDS ----------------
__global__ __launch_bounds__(256) void k_gemm(
        const float* __restrict__ x, const __bf16* __restrict__ whi,
        const __bf16* __restrict__ wlo, const float* __restrict__ dinv,
        __bf16* __restrict__ yb, int n) {
    int wave = threadIdx.x >> 6;
    int lane = threadIdx.x & 63;
    int m0 = blockIdx.x * 64 + wave * 16;
    if (m0 >= n) return;
    int q = lane >> 4, cl = lane & 15;
    int arow = m0 + cl; if (arow >= n) arow = n - 1;   // clamp (tail rows unused)
    const float* ap = x + (size_t)arow * D_IN + q * 8;

    floatx4 acc[4] = {{0.f,0.f,0.f,0.f},{0.f,0.f,0.f,0.f},
                      {0.f,0.f,0.f,0.f},{0.f,0.f,0.f,0.f}};

    #pragma unroll
    for (int c = 0; c < 8; ++c) {
        floatx4 a0 = *(const floatx4*)(ap + c * 32);
        floatx4 a1 = *(const floatx4*)(ap + c * 32 + 4);
        bf16x8 ahi, alo;
        #pragma unroll
        for (int j = 0; j < 4; ++j) {
            __bf16 h0 = (__bf16)a0[j];
            __bf16 h1 = (__bf16)a1[j];
            ahi[j] = h0;     alo[j] = (__bf16)(a0[j] - (float)h0);
            ahi[4 + j] = h1; alo[4 + j] = (__bf16)(a1[j] - (float)h1);
        }
        #pragma unroll
        for (int t = 0; t < 4; ++t) {
            size_t fo = ((size_t)(t * 8 + c) * 64 + lane) * 8;
            bf16x8 bh = *(const bf16x8*)(whi + fo);
            bf16x8 bl = *(const bf16x8*)(wlo + fo);
            acc[t] = __builtin_amdgcn_mfma_f32_16x16x32_bf16(ahi, bh, acc[t], 0, 0, 0);
            acc[t] = __builtin_amdgcn_mfma_f32_16x16x32_bf16(alo, bh, acc[t], 0, 0, 0);
            acc[t] = __builtin_amdgcn_mfma_f32_16x16x32_bf16(ahi, bl, acc[t], 0, 0, 0);
        }
    }

    int nb = m0 + q * 4;
    float dv[4];
    #pragma unroll
    for (int r = 0; r < 4; ++r) dv[r] = (nb + r < n) ? dinv[nb + r] : 0.f;
    #pragma unroll
    for (int t = 0; t < 4; ++t) {
        #pragma unroll
        for (int r = 0; r < 4; ++r) {
            int node = nb + r;
            if (node < n)
                yb[(size_t)node * D_OUT + t * 16 + cl] = (__bf16)(dv[r] * acc[t][r]);
        }
    }
}

// ---- CSR gather-aggregate: eighth-wave per edge, b128 loads ----------------
// Wave per node; group of 8 lanes per edge row; lane = 8 channels (uint4 = 16B).
__device__ __forceinline__ void acc_row4(uintx4 v, float (&a)[8]) {
    #pragma unroll
    for (int k = 0; k < 4; ++k) {
        a[2 * k]     += __uint_as_float(v[k] << 16);
        a[2 * k + 1] += __uint_as_float(v[k] & 0xffff0000u);
    }
}

__global__ __launch_bounds__(256) void k_aggregate(
        const int* __restrict__ off, const int* __restrict__ srcs,
        const unsigned* __restrict__ ybf, const float* __restrict__ dinv,
        const float* __restrict__ bnsc, const float* __restrict__ bnsh,
        float* __restrict__ out, int n) {
    int node = blockIdx.x * 4 + (threadIdx.x >> 6);
    if (node >= n) return;
    int lane = threadIdx.x & 63;
    int g = lane >> 3, sl = lane & 7;        // edge-group, sub-lane (8 channels)
    int s = off[node], e2 = off[node + 1];

    float a[8] = {0.f, 0.f, 0.f, 0.f, 0.f, 0.f, 0.f, 0.f};
    float dv = 0.f;
    floatx4 bs0, bs1, bh0, bh1;
    if (g == 0) {                            // self-loop + epilogue params
        dv = dinv[node];
        bs0 = *(const floatx4*)(bnsc + sl * 8);
        bs1 = *(const floatx4*)(bnsc + sl * 8 + 4);
        bh0 = *(const floatx4*)(bnsh + sl * 8);
        bh1 = *(const floatx4*)(bnsh + sl * 8 + 4);
        uintx4 v = *(const uintx4*)(ybf + (size_t)node * 32 + sl * 4);
        acc_row4(v, a);
    }

    int e = s + g;
    for (; e + 24 < e2; e += 32) {           // 4 rows in flight per group
        int r0 = srcs[e], r1 = srcs[e + 8], r2 = srcs[e + 16], r3 = srcs[e + 24];
        uintx4 v0 = *(const uintx4*)(ybf + (size_t)r0 * 32 + sl * 4);
        uintx4 v1 = *(const uintx4*)(ybf + (size_t)r1 * 32 + sl * 4);
        uintx4 v2 = *(const uintx4*)(ybf + (size_t)r2 * 32 + sl * 4);
        uintx4 v3 = *(const uintx4*)(ybf + (size_t)r3 * 32 + sl * 4);
        acc_row4(v0, a);
        acc_row4(v1, a);
        acc_row4(v2, a);
        acc_row4(v3, a);
    }
    for (; e + 8 < e2; e += 16) {            // 2 rows in flight
        int r0 = srcs[e], r1 = srcs[e + 8];
        uintx4 v0 = *(const uintx4*)(ybf + (size_t)r0 * 32 + sl * 4);
        uintx4 v1 = *(const uintx4*)(ybf + (size_t)r1 * 32 + sl * 4);
        acc_row4(v0, a);
        acc_row4(v1, a);
    }
    for (; e < e2; e += 8) {
        uintx4 v = *(const uintx4*)(ybf + (size_t)srcs[e] * 32 + sl * 4);
        acc_row4(v, a);
    }

    #pragma unroll
    for (int k = 0; k < 8; ++k) {
        a[k] += __shfl_xor(a[k], 8);
        a[k] += __shfl_xor(a[k], 16);
        a[k] += __shfl_xor(a[k], 32);
    }

    if (g == 0) {
        float o[8];
        #pragma unroll
        for (int k = 0; k < 4; ++k) {
            o[k]     = fmaf(dv * a[k],     bs0[k], bh0[k]);
            o[4 + k] = fmaf(dv * a[4 + k], bs1[k], bh1[k]);
        }
        floatx4 w0 = { fmaxf(o[0], 0.f), fmaxf(o[1], 0.f),
                       fmaxf(o[2], 0.f), fmaxf(o[3], 0.f) };
        floatx4 w1 = { fmaxf(o[4], 0.f), fmaxf(o[5], 0.f),
                       fmaxf(o[6], 0.f), fmaxf(o[7], 0.f) };
        *(floatx4*)(out + (size_t)node * D_OUT + sl * 8) = w0;
        *(floatx4*)(out + (size_t)node * D_OUT + sl * 8 + 4) = w1;
    }
}

static inline char* align_up(char* p, size_t a) {
    return (char*)(((uintptr_t)p + a - 1) & ~(uintptr_t)(a - 1));
}

extern "C" void kernel_launch(void* const* d_in, const int* in_sizes, int n_in,
                              void* d_out, int out_size, void* d_ws, size_t ws_size,
                              hipStream_t stream) {
    const float* x     = (const float*)d_in[0];
    const int*   ei    = (const int*)d_in[1];
    const float* W     = (const float*)d_in[2];
    const float* bias  = (const float*)d_in[3];
    const float* gamma = (const float*)d_in[4];
    const float* beta  = (const float*)d_in[5];
    const float* rmean = (const float*)d_in[6];
    const float* rvar  = (const float*)d_in[7];
    float* out = (float*)d_out;

    int N = in_sizes[0] / D_IN;
    int E = in_sizes[1] / 2;
    int nbins = (N + (1 << BINSHIFT) - 1) >> BINSHIFT;   // 391 for N=100000

    char* p = (char*)d_ws;
    int*      bincur = (int*)p;         p += 512 * 4;
    int*      binoff = (int*)p;         p += 512 * 4;
    int*      off    = (int*)p;         p += (size_t)(N + 1) * 4; p = align_up(p, 256);
    float*    dinv   = (float*)p;       p += (size_t)N * 4;       p = align_up(p, 256);
    float*    bnsc   = (float*)p;       p += D_OUT * 4;
    float*    bnsh   = (float*)p;       p += D_OUT * 4;           p = align_up(p, 256);
    __bf16*   whi    = (__bf16*)p;      p += (size_t)D_OUT * D_IN * 2; p = align_up(p, 256);
    __bf16*   wlo    = (__bf16*)p;      p += (size_t)D_OUT * D_IN * 2; p = align_up(p, 256);
    __bf16*   yb     = (__bf16*)p;      p += (size_t)N * D_OUT * 2;    p = align_up(p, 256);
    int*      srcs   = (int*)p;         p += (size_t)E * 4;       p = align_up(p, 256);
    unsigned* pairs  = (unsigned*)p;    // nbins * BINCAP * 4 bytes (~7.2 MB)

    k_prep<<<10, 256, 0, stream>>>(W, whi, wlo, bias, gamma, beta, rmean, rvar,
                                   bnsc, bnsh, bincur, nbins);

    {   // fused partition + scan + CSR fill (grid-wide sync, 391 blocks co-resident)
        void* args[] = { (void*)&ei, (void*)&bincur, (void*)&pairs,
                         (void*)&binoff, (void*)&off, (void*)&dinv,
                         (void*)&srcs, (void*)&E, (void*)&N, (void*)&nbins };
        hipLaunchCooperativeKernel((void*)k_build, dim3(nbins), dim3(256),
                                   args, 0, stream);
    }

    k_gemm<<<(N + 63) / 64, 256, 0, stream>>>(x, whi, wlo, dinv, yb, N);
    k_aggregate<<<(N + 3) / 4, 256, 0, stream>>>(off, srcs, (const unsigned*)yb,
                                                 dinv, bnsc, bnsh, out, N);
}

// Round 8
// 286.975 us; speedup vs baseline: 1.4116x; 1.4116x over previous
//
#include <hip/hip_runtime.h>
#include <hip/hip_bf16.h>

#define D_IN 256
#define D_OUT 64
#define BN_EPS 1e-5f

#define BINSHIFT 8                 // 256 nodes per bin
#define BINCAP 4608                // >= max edges per bin (mean 4092, +8 sigma)
#define PCHUNK 8192                // edges per k_part block

typedef __attribute__((ext_vector_type(4))) float floatx4;
typedef __attribute__((ext_vector_type(8))) __bf16 bf16x8;
typedef __attribute__((ext_vector_type(4))) unsigned uintx4;

// ---- prep: zero bincur + bn params + W split (MFMA B-fragment order) -------
__global__ __launch_bounds__(256) void k_prep(
        const float* __restrict__ W, __bf16* __restrict__ whi, __bf16* __restrict__ wlo,
        const float* __restrict__ bias, const float* __restrict__ gamma,
        const float* __restrict__ beta, const float* __restrict__ rmean,
        const float* __restrict__ rvar,
        float* __restrict__ bnsc, float* __restrict__ bnsh,
        int* __restrict__ bincur, int nbins) {
    int b = blockIdx.x, t = threadIdx.x;
    if (b < 2) {
        int i = b * 256 + t;
        if (i < nbins) bincur[i] = 0;
        if (b == 1 && t < D_OUT) {
            float sc = rsqrtf(rvar[t] + BN_EPS) * gamma[t];
            bnsc[t] = sc;
            bnsh[t] = (bias[t] - rmean[t]) * sc + beta[t];
        }
        return;
    }
    int tid = (b - 2) * 256 + t;   // 0..2047
    int lane = tid & 63, c = (tid >> 6) & 7, tt = tid >> 9;
    int row = tt * 16 + (lane & 15);
    int k0 = c * 32 + (lane >> 4) * 8;
    size_t dst = (size_t)tid * 8;
    #pragma unroll
    for (int j = 0; j < 8; ++j) {
        float w = W[(size_t)row * D_IN + k0 + j];
        __bf16 h = (__bf16)w;
        whi[dst + j] = h;
        wlo[dst + j] = (__bf16)(w - (float)h);
    }
}

// ---- binned partition: packed (src<<8 | tgt&255) into bin segments ---------
__global__ __launch_bounds__(256) void k_part(
        const int* __restrict__ ei, int* __restrict__ bincur,
        unsigned* __restrict__ pairs, int E, int nbins) {
    __shared__ int hist[512];
    __shared__ int base[512];
    int t = threadIdx.x;
    int e0 = blockIdx.x * PCHUNK;

    for (int j = t; j < nbins; j += 256) hist[j] = 0;
    __syncthreads();

    int cols[PCHUNK / 256];
    int ranks[PCHUNK / 256];
    #pragma unroll
    for (int i = 0; i < PCHUNK / 256; ++i) {
        int e = e0 + i * 256 + t;
        if (e < E) {
            int c = ei[E + e];
            cols[i] = c;
            ranks[i] = atomicAdd(&hist[c >> BINSHIFT], 1);
        }
    }
    __syncthreads();
    for (int j = t; j < nbins; j += 256)
        base[j] = atomicAdd(&bincur[j], hist[j]);
    __syncthreads();
    #pragma unroll
    for (int i = 0; i < PCHUNK / 256; ++i) {
        int e = e0 + i * 256 + t;
        if (e < E) {
            int c = cols[i];
            int bin = c >> BINSHIFT;
            int pos = base[bin] + ranks[i];
            if (pos >= BINCAP) pos = BINCAP - 1;     // never-hit safety
            pairs[(size_t)bin * BINCAP + pos] =
                ((unsigned)ei[e] << 8) | (unsigned)(c & 255);
        }
    }
}

// ---- per-bin CSR fill, with the bin-offset scan fused in -------------------
// Phase A: every block redundantly exclusive-scans bincur[0..nbins) in LDS
//          (391 ints, ~1.6KB) and keeps only its own bin's offset. Block 0
//          writes off[N] = E. Replaces the former 1-block k_binscan kernel.
// Phase B: node-level counts -> off/dinv (local scan) -> CSR scatter.
__global__ __launch_bounds__(256) void k_fill3(
        const unsigned* __restrict__ pairs, const int* __restrict__ bincur,
        int* __restrict__ off, float* __restrict__ dinv,
        int* __restrict__ srcs, int n, int nbins) {
    __shared__ int hist[256];
    __shared__ int sc[256];
    __shared__ int curs[256];
    __shared__ int sbase;
    int bin = blockIdx.x, t = threadIdx.x;

    // ---- phase A: redundant per-block scan of bin counts ----
    int i0 = 2 * t, i1 = 2 * t + 1;
    int v0 = (i0 < nbins) ? bincur[i0] : 0;
    int v1 = (i1 < nbins) ? bincur[i1] : 0;
    int s = v0 + v1;
    sc[t] = s;
    hist[t] = 0;                      // init for phase B
    __syncthreads();
    for (int o = 1; o < 256; o <<= 1) {
        int v = (t >= o) ? sc[t - o] : 0;
        __syncthreads();
        sc[t] += v;
        __syncthreads();
    }
    int excl = sc[t] - s;
    if (t == (bin >> 1)) sbase = (bin & 1) ? (excl + v0) : excl;
    if (bin == 0 && t == 255) off[n] = sc[255];
    __syncthreads();
    int binoff_b = sbase;

    // ---- phase B: per-bin node histogram -> off/dinv -> CSR scatter ----
    int cnt = bincur[bin];
    const unsigned* bp = pairs + (size_t)bin * BINCAP;
    for (int p = t; p < cnt; p += 256)
        atomicAdd(&hist[bp[p] & 255u], 1);
    __syncthreads();
    int own = hist[t];
    sc[t] = own;
    __syncthreads();
    for (int o = 1; o < 256; o <<= 1) {
        int v = (t >= o) ? sc[t - o] : 0;
        __syncthreads();
        sc[t] += v;
        __syncthreads();
    }
    int base = binoff_b + sc[t] - own;
    int node = (bin << BINSHIFT) + t;
    curs[t] = base;
    if (node < n) {
        off[node] = base;
        dinv[node] = rsqrtf((float)(own + 1));   // +1 self-loop
    }
    __syncthreads();
    for (int p = t; p < cnt; p += 256) {
        unsigned v = bp[p];
        int pos = atomicAdd(&curs[v & 255u], 1);
        srcs[pos] = (int)(v >> 8);
    }
}

// ---- y(bf16) = dinv * (x @ W^T) via split-bf16 MFMA; no LDS ----------------
__global__ __launch_bounds__(256) void k_gemm(
        const float* __restrict__ x, const __bf16* __restrict__ whi,
        const __bf16* __restrict__ wlo, const float* __restrict__ dinv,
        __bf16* __restrict__ yb, int n) {
    int wave = threadIdx.x >> 6;
    int lane = threadIdx.x & 63;
    int m0 = blockIdx.x * 64 + wave * 16;
    if (m0 >= n) return;
    int q = lane >> 4, cl = lane & 15;
    int arow = m0 + cl; if (arow >= n) arow = n - 1;   // clamp (tail rows unused)
    const float* ap = x + (size_t)arow * D_IN + q * 8;

    floatx4 acc[4] = {{0.f,0.f,0.f,0.f},{0.f,0.f,0.f,0.f},
                      {0.f,0.f,0.f,0.f},{0.f,0.f,0.f,0.f}};

    #pragma unroll
    for (int c = 0; c < 8; ++c) {
        floatx4 a0 = *(const floatx4*)(ap + c * 32);
        floatx4 a1 = *(const floatx4*)(ap + c * 32 + 4);
        bf16x8 ahi, alo;
        #pragma unroll
        for (int j = 0; j < 4; ++j) {
            __bf16 h0 = (__bf16)a0[j];
            __bf16 h1 = (__bf16)a1[j];
            ahi[j] = h0;     alo[j] = (__bf16)(a0[j] - (float)h0);
            ahi[4 + j] = h1; alo[4 + j] = (__bf16)(a1[j] - (float)h1);
        }
        #pragma unroll
        for (int t = 0; t < 4; ++t) {
            size_t fo = ((size_t)(t * 8 + c) * 64 + lane) * 8;
            bf16x8 bh = *(const bf16x8*)(whi + fo);
            bf16x8 bl = *(const bf16x8*)(wlo + fo);
            acc[t] = __builtin_amdgcn_mfma_f32_16x16x32_bf16(ahi, bh, acc[t], 0, 0, 0);
            acc[t] = __builtin_amdgcn_mfma_f32_16x16x32_bf16(alo, bh, acc[t], 0, 0, 0);
            acc[t] = __builtin_amdgcn_mfma_f32_16x16x32_bf16(ahi, bl, acc[t], 0, 0, 0);
        }
    }

    int nb = m0 + q * 4;
    float dv[4];
    #pragma unroll
    for (int r = 0; r < 4; ++r) dv[r] = (nb + r < n) ? dinv[nb + r] : 0.f;
    #pragma unroll
    for (int t = 0; t < 4; ++t) {
        #pragma unroll
        for (int r = 0; r < 4; ++r) {
            int node = nb + r;
            if (node < n)
                yb[(size_t)node * D_OUT + t * 16 + cl] = (__bf16)(dv[r] * acc[t][r]);
        }
    }
}

// ---- CSR gather-aggregate: eighth-wave per edge, b128 loads ----------------
__device__ __forceinline__ void acc_row4(uintx4 v, float (&a)[8]) {
    #pragma unroll
    for (int k = 0; k < 4; ++k) {
        a[2 * k]     += __uint_as_float(v[k] << 16);
        a[2 * k + 1] += __uint_as_float(v[k] & 0xffff0000u);
    }
}

__global__ __launch_bounds__(256) void k_aggregate(
        const int* __restrict__ off, const int* __restrict__ srcs,
        const unsigned* __restrict__ ybf, const float* __restrict__ dinv,
        const float* __restrict__ bnsc, const float* __restrict__ bnsh,
        float* __restrict__ out, int n) {
    int node = blockIdx.x * 4 + (threadIdx.x >> 6);
    if (node >= n) return;
    int lane = threadIdx.x & 63;
    int g = lane >> 3, sl = lane & 7;        // edge-group, sub-lane (8 channels)
    int s = off[node], e2 = off[node + 1];

    float a[8] = {0.f, 0.f, 0.f, 0.f, 0.f, 0.f, 0.f, 0.f};
    float dv = 0.f;
    floatx4 bs0, bs1, bh0, bh1;
    if (g == 0) {                            // self-loop + epilogue params
        dv = dinv[node];
        bs0 = *(const floatx4*)(bnsc + sl * 8);
        bs1 = *(const floatx4*)(bnsc + sl * 8 + 4);
        bh0 = *(const floatx4*)(bnsh + sl * 8);
        bh1 = *(const floatx4*)(bnsh + sl * 8 + 4);
        uintx4 v = *(const uintx4*)(ybf + (size_t)node * 32 + sl * 4);
        acc_row4(v, a);
    }

    int e = s + g;
    for (; e + 24 < e2; e += 32) {           // 4 rows in flight per group
        int r0 = srcs[e], r1 = srcs[e + 8], r2 = srcs[e + 16], r3 = srcs[e + 24];
        uintx4 v0 = *(const uintx4*)(ybf + (size_t)r0 * 32 + sl * 4);
        uintx4 v1 = *(const uintx4*)(ybf + (size_t)r1 * 32 + sl * 4);
        uintx4 v2 = *(const uintx4*)(ybf + (size_t)r2 * 32 + sl * 4);
        uintx4 v3 = *(const uintx4*)(ybf + (size_t)r3 * 32 + sl * 4);
        acc_row4(v0, a);
        acc_row4(v1, a);
        acc_row4(v2, a);
        acc_row4(v3, a);
    }
    for (; e + 8 < e2; e += 16) {            // 2 rows in flight
        int r0 = srcs[e], r1 = srcs[e + 8];
        uintx4 v0 = *(const uintx4*)(ybf + (size_t)r0 * 32 + sl * 4);
        uintx4 v1 = *(const uintx4*)(ybf + (size_t)r1 * 32 + sl * 4);
        acc_row4(v0, a);
        acc_row4(v1, a);
    }
    for (; e < e2; e += 8) {
        uintx4 v = *(const uintx4*)(ybf + (size_t)srcs[e] * 32 + sl * 4);
        acc_row4(v, a);
    }

    #pragma unroll
    for (int k = 0; k < 8; ++k) {
        a[k] += __shfl_xor(a[k], 8);
        a[k] += __shfl_xor(a[k], 16);
        a[k] += __shfl_xor(a[k], 32);
    }

    if (g == 0) {
        float o[8];
        #pragma unroll
        for (int k = 0; k < 4; ++k) {
            o[k]     = fmaf(dv * a[k],     bs0[k], bh0[k]);
            o[4 + k] = fmaf(dv * a[4 + k], bs1[k], bh1[k]);
        }
        floatx4 w0 = { fmaxf(o[0], 0.f), fmaxf(o[1], 0.f),
                       fmaxf(o[2], 0.f), fmaxf(o[3], 0.f) };
        floatx4 w1 = { fmaxf(o[4], 0.f), fmaxf(o[5], 0.f),
                       fmaxf(o[6], 0.f), fmaxf(o[7], 0.f) };
        *(floatx4*)(out + (size_t)node * D_OUT + sl * 8) = w0;
        *(floatx4*)(out + (size_t)node * D_OUT + sl * 8 + 4) = w1;
    }
}

static inline char* align_up(char* p, size_t a) {
    return (char*)(((uintptr_t)p + a - 1) & ~(uintptr_t)(a - 1));
}

extern "C" void kernel_launch(void* const* d_in, const int* in_sizes, int n_in,
                              void* d_out, int out_size, void* d_ws, size_t ws_size,
                              hipStream_t stream) {
    const float* x     = (const float*)d_in[0];
    const int*   ei    = (const int*)d_in[1];
    const float* W     = (const float*)d_in[2];
    const float* bias  = (const float*)d_in[3];
    const float* gamma = (const float*)d_in[4];
    const float* beta  = (const float*)d_in[5];
    const float* rmean = (const float*)d_in[6];
    const float* rvar  = (const float*)d_in[7];
    float* out = (float*)d_out;

    int N = in_sizes[0] / D_IN;
    int E = in_sizes[1] / 2;
    int nbins = (N + (1 << BINSHIFT) - 1) >> BINSHIFT;   // 391 for N=100000

    char* p = (char*)d_ws;
    int*      bincur = (int*)p;         p += 512 * 4;
    int*      off    = (int*)p;         p += (size_t)(N + 1) * 4; p = align_up(p, 256);
    float*    dinv   = (float*)p;       p += (size_t)N * 4;       p = align_up(p, 256);
    float*    bnsc   = (float*)p;       p += D_OUT * 4;
    float*    bnsh   = (float*)p;       p += D_OUT * 4;           p = align_up(p, 256);
    __bf16*   whi    = (__bf16*)p;      p += (size_t)D_OUT * D_IN * 2; p = align_up(p, 256);
    __bf16*   wlo    = (__bf16*)p;      p += (size_t)D_OUT * D_IN * 2; p = align_up(p, 256);
    __bf16*   yb     = (__bf16*)p;      p += (size_t)N * D_OUT * 2;    p = align_up(p, 256);
    int*      srcs   = (int*)p;         p += (size_t)E * 4;       p = align_up(p, 256);
    unsigned* pairs  = (unsigned*)p;    // nbins * BINCAP * 4 bytes (~7.2 MB)

    k_prep<<<10, 256, 0, stream>>>(W, whi, wlo, bias, gamma, beta, rmean, rvar,
                                   bnsc, bnsh, bincur, nbins);
    k_part<<<(E + PCHUNK - 1) / PCHUNK, 256, 0, stream>>>(ei, bincur, pairs, E, nbins);
    k_fill3<<<nbins, 256, 0, stream>>>(pairs, bincur, off, dinv, srcs, N, nbins);
    k_gemm<<<(N + 63) / 64, 256, 0, stream>>>(x, whi, wlo, dinv, yb, N);
    k_aggregate<<<(N + 3) / 4, 256, 0, stream>>>(off, srcs, (const unsigned*)yb,
                                                 dinv, bnsc, bnsh, out, N);
}